// Round 12
// baseline (444.865 us; speedup 1.0000x reference)
//
#include <hip/hip_runtime.h>

// PSP: syn_t = 0.5*(syn_{t-1} + x_t), tau=2. Shapes (T=64, N=512, C=2048) f32.
//
// R1-R11 lesson: EVERY single-kernel structure (drip, reg-batch, chunked-reg,
// LDS-staged 4KB runs) lands at ~165-180us (~3 TB/s) while fills hit 6.5.
// Theory: DRAM row-hit rate. Blocks drift out of chunk-phase, so each 4MB
// slab sees a sparse set of 1KB islands -> ~1 row-activate per 256B chunk.
// Fix: chunk-lockstep via KERNEL BOUNDARIES. 4 sequential launches of 16
// slabs each; within a launch all resident blocks sweep the SAME 16 slabs
// with consecutive (XCD-swizzled) windows -> dense per-slab access front.
// Carry chains through `out`: kernel c loads out[slab 16c-1] (exact f32
// written by kernel c-1; sequential kernels on a stream give visibility).
// Recurrence is bit-exact (same op order as reference) -> absmax 0.

typedef float f4 __attribute__((ext_vector_type(4)));

#define NC4 (512 * 2048 / 4)   // 262144 f4 columns per timestep
#define CHUNK 16               // timesteps per kernel launch
#define NBLK 1024              // blocks; 256 threads * f4 = 1024 cols/block

__global__ __launch_bounds__(256) void psp_chunk_kernel(
    const f4* __restrict__ in, f4* __restrict__ out, int t0) {
    // XCD swizzle (1024 % 8 == 0): XCD k owns 128 consecutive windows ->
    // the XCD's instantaneous read front per slab is ~512KB contiguous.
    const int bid = blockIdx.x;
    const int win = (bid & 7) * (NBLK / 8) + (bid >> 3);
    const int col = win * 256 + (int)threadIdx.x;     // f4-column id

    const f4* ip = in  + (size_t)t0 * NC4 + col;
    f4*       op = out + (size_t)t0 * NC4 + col;

    // Carry first (hides under the 16 slab loads). L3-hot for t0>0.
    f4 acc = {0.f, 0.f, 0.f, 0.f};
    if (t0 > 0) acc = out[(size_t)(t0 - 1) * NC4 + col];

    // 16 independent slab loads.
    f4 v[CHUNK];
#pragma unroll
    for (int j = 0; j < CHUNK; ++j)
        v[j] = ip[(size_t)j * NC4];

    // Exact serial recurrence.
#pragma unroll
    for (int j = 0; j < CHUNK; ++j) {
        acc = 0.5f * (acc + v[j]);
        v[j] = acc;
    }

    // 16 stores.
#pragma unroll
    for (int j = 0; j < CHUNK; ++j)
        op[(size_t)j * NC4] = v[j];
}

extern "C" void kernel_launch(void* const* d_in, const int* in_sizes, int n_in,
                              void* d_out, int out_size, void* d_ws, size_t ws_size,
                              hipStream_t stream) {
    const f4* in = (const f4*)d_in[0];
    f4* out = (f4*)d_out;
    // 4 sequential chunk kernels; stream order provides the carry dependency
    // and a cheap grid-wide "barrier" that keeps all blocks chunk-locked.
    for (int c = 0; c < 4; ++c)
        psp_chunk_kernel<<<NBLK, 256, 0, stream>>>(in, out, c * CHUNK);
}